// Round 1
// baseline (772.929 us; speedup 1.0000x reference)
//
#include <hip/hip_runtime.h>
#include <stdint.h>

// Problem: out[b,s,o] = sum_i x[b,s,i] * (W[o,i] + sum_r A[o,r]*B[r,i]) + bias[o]
// M = 4*4096 = 16384, N = 4096, K = 4096.  All fp32 in/out; compute in bf16 MFMA.

#define MDIM 16384
#define NDIM 4096
#define KDIM 4096
#define RANK 16

typedef __bf16  bf16x8 __attribute__((ext_vector_type(8)));
typedef float   f32x4  __attribute__((ext_vector_type(4)));
typedef unsigned short u16x8 __attribute__((ext_vector_type(8)));

// RNE float -> bf16 (finite inputs)
__device__ __forceinline__ unsigned short f2bf(float f) {
  union { float f; uint32_t u; } v; v.f = f;
  uint32_t r = v.u + 0x7FFFu + ((v.u >> 16) & 1u);
  return (unsigned short)(r >> 16);
}

// async global->LDS, 16 bytes per lane (lands at wave-uniform base + lane*16)
__device__ __forceinline__ void gl16(const void* g, void* l) {
  __builtin_amdgcn_global_load_lds(
      (__attribute__((address_space(1))) void*)(g),
      (__attribute__((address_space(3))) void*)(l),
      16, 0, 0);
}

// Wp[o][i] = bf16(W[o][i] + sum_r A[o][r]*B[r][i])
__global__ void prep_w(const float* __restrict__ W, const float* __restrict__ A,
                       const float* __restrict__ Bm, unsigned short* __restrict__ Wp) {
  const int i = blockIdx.x * 256 + threadIdx.x;
  const int o = blockIdx.y;
  float acc = W[(size_t)o * NDIM + i];
#pragma unroll
  for (int r = 0; r < RANK; ++r)
    acc += A[o * RANK + r] * Bm[(size_t)r * NDIM + i];
  Wp[(size_t)o * NDIM + i] = f2bf(acc);
}

// x fp32 -> bf16, 8 elems/thread
__global__ void cast_x(const float* __restrict__ x, unsigned short* __restrict__ xb) {
  const size_t i = ((size_t)blockIdx.x * 256 + threadIdx.x) * 8;
  float4 a = *(const float4*)(x + i);
  float4 b = *(const float4*)(x + i + 4);
  u16x8 o;
  o[0] = f2bf(a.x); o[1] = f2bf(a.y); o[2] = f2bf(a.z); o[3] = f2bf(a.w);
  o[4] = f2bf(b.x); o[5] = f2bf(b.y); o[6] = f2bf(b.z); o[7] = f2bf(b.w);
  *(u16x8*)(xb + i) = o;
}

// C = Xb [M][K] @ Wp[N][K]^T + bias, fp32 out.  m97 structure:
// 128x128 tile, 4 waves, each wave a 64x64 quadrant of 4x4 16x16 fragments,
// BK=32, single-buffer LDS, global_load_lds width-16 staging.
__global__ __launch_bounds__(256) void gemm_bt(
    const unsigned short* __restrict__ Xb,
    const unsigned short* __restrict__ Wp,
    const float* __restrict__ bias,
    float* __restrict__ out) {
  __shared__ __align__(16) unsigned short sA[128 * 32];
  __shared__ __align__(16) unsigned short sB[128 * 32];

  const int t  = threadIdx.x;
  const int w  = t >> 6;
  const int l  = t & 63;
  const int wr = w >> 1;       // wave row  (0..1)
  const int wc = w & 1;        // wave col  (0..1)
  const int lr = l & 15;       // fragment row/col index
  const int kh = (l >> 4) * 8; // k-offset of this lane's 8 elements

  const int bm = blockIdx.y * 128;
  const int bn = blockIdx.x * 128;

  // staging: thread t loads 8 bf16 (16B) at [row = t/4][k = (t%4)*8], rounds r=0,1 add 64 rows
  const int srow  = t >> 2;
  const int skoff = (t & 3) * 8;
  const unsigned short* ag = Xb + (size_t)(bm + srow) * KDIM + skoff;
  const unsigned short* bg = Wp + (size_t)(bn + srow) * KDIM + skoff;
  unsigned short* la = &sA[t * 8];
  unsigned short* lb = &sB[t * 8];

  f32x4 acc[4][4];
#pragma unroll
  for (int i = 0; i < 4; ++i)
#pragma unroll
    for (int j = 0; j < 4; ++j)
      acc[i][j] = f32x4{0.f, 0.f, 0.f, 0.f};

  for (int kt = 0; kt < KDIM / 32; ++kt) {
    const int ko = kt * 32;
    __syncthreads();  // previous iter's LDS reads done
    gl16(ag + ko, la);
    gl16(ag + (size_t)64 * KDIM + ko, la + 2048);
    gl16(bg + ko, lb);
    gl16(bg + (size_t)64 * KDIM + ko, lb + 2048);
    __syncthreads();  // staging drained (compiler emits vmcnt(0) before barrier)

    bf16x8 af[4], bfr[4];
#pragma unroll
    for (int mi = 0; mi < 4; ++mi)
      af[mi] = *(const bf16x8*)&sA[(wr * 64 + mi * 16 + lr) * 32 + kh];
#pragma unroll
    for (int ni = 0; ni < 4; ++ni)
      bfr[ni] = *(const bf16x8*)&sB[(wc * 64 + ni * 16 + lr) * 32 + kh];
#pragma unroll
    for (int mi = 0; mi < 4; ++mi)
#pragma unroll
      for (int ni = 0; ni < 4; ++ni)
        acc[mi][ni] = __builtin_amdgcn_mfma_f32_16x16x32_bf16(af[mi], bfr[ni], acc[mi][ni], 0, 0, 0);
  }

  // epilogue: C/D layout col=lane&15, row=(lane>>4)*4+reg
#pragma unroll
  for (int mi = 0; mi < 4; ++mi) {
#pragma unroll
    for (int ni = 0; ni < 4; ++ni) {
      const int row = bm + wr * 64 + mi * 16 + (l >> 4) * 4;
      const int col = bn + wc * 64 + ni * 16 + lr;
      const float bv = bias[col];
#pragma unroll
      for (int r = 0; r < 4; ++r)
        out[(size_t)(row + r) * NDIM + col] = acc[mi][ni][r] + bv;
    }
  }
}

extern "C" void kernel_launch(void* const* d_in, const int* in_sizes, int n_in,
                              void* d_out, int out_size, void* d_ws, size_t ws_size,
                              hipStream_t stream) {
  const float* x    = (const float*)d_in[0];
  const float* W    = (const float*)d_in[1];
  const float* bias = (const float*)d_in[2];
  const float* A    = (const float*)d_in[3];
  const float* B    = (const float*)d_in[4];
  float* out        = (float*)d_out;

  unsigned short* Wp = (unsigned short*)d_ws;                       // 4096*4096*2  = 32 MiB
  unsigned short* Xb = (unsigned short*)d_ws + (size_t)NDIM * KDIM; // 16384*4096*2 = 128 MiB

  prep_w<<<dim3(NDIM / 256, NDIM), 256, 0, stream>>>(W, A, B, Wp);
  cast_x<<<dim3((size_t)MDIM * KDIM / (256 * 8)), 256, 0, stream>>>(x, Xb);
  gemm_bt<<<dim3(NDIM / 128, MDIM / 128), 256, 0, stream>>>(Xb, Wp, bias, out);
}